// Round 3
// baseline (1430.144 us; speedup 1.0000x reference)
//
#include <hip/hip_runtime.h>

#define M_DIM 8192
#define N_DIM 11008
#define K_DIM 4096
#define GROUPS 32     // K / 128
#define LDSK 72       // slow kernel pad

typedef short s16x8 __attribute__((ext_vector_type(8)));
typedef float f32x4 __attribute__((ext_vector_type(4)));
typedef unsigned short u16;
typedef unsigned int u32;

union f32u { float f; unsigned u; };
union h16u { u16 u; _Float16 h; };

__device__ __forceinline__ u16 f2bf(float f) {
  f32u v; v.f = f;
  unsigned r = v.u + 0x7FFFu + ((v.u >> 16) & 1u);  // RNE
  return (u16)(r >> 16);
}
__device__ __forceinline__ float bf2f(u16 b) {
  f32u v; v.u = ((unsigned)b) << 16; return v.f;
}
__device__ __forceinline__ float h2f(u16 b) {
  h16u v; v.u = b; return (float)v.h;
}
__device__ __forceinline__ float magicf(u32 bits) {
  f32u v; v.u = bits; return v.f;
}
__device__ __forceinline__ u32 cvt_pk_bf16(float lo, float hi) {
  u32 r;
  asm("v_cvt_pk_bf16_f32 %0, %1, %2" : "=v"(r) : "v"(lo), "v"(hi));
  return r;
}

// ---------------------------------------------------------------------------
// Probe: classify storage of the fp16-in-reference buffers (see R0/R2 notes).
// Empirically (R2): harness delivers bf16 -> expect mode 2.
// ---------------------------------------------------------------------------
__global__ void probe_mode_kernel(const void* __restrict__ scales,
                                  int* __restrict__ mode_out) {
  __shared__ int cnt[3];
  int t = threadIdx.x;
  if (t < 3) cnt[t] = 0;
  __syncthreads();
  float f0 = ((const float*)scales)[t];
  u16  hu  = ((const u16*)scales)[t];
  float f1 = h2f(hu);
  float f2 = bf2f(hu);
  if (f0 > 0.0004f && f0 < 0.065f) atomicAdd(&cnt[0], 1);
  if (f1 > 0.0004f && f1 < 0.065f) atomicAdd(&cnt[1], 1);
  if (f2 > 0.0004f && f2 < 0.065f) atomicAdd(&cnt[2], 1);
  __syncthreads();
  if (t == 0) {
    int m;
    if      (cnt[1] >= 240) m = 1;  // raw fp16 bits
    else if (cnt[2] >= 240) m = 2;  // raw bf16 bits
    else                    m = 0;  // f32
    mode_out[0] = m;
  }
}

// ---------------------------------------------------------------------------
// In-register dequant: one int4 = 4 dwords, each dword's LOW BYTE = 2 nibbles
// (low nibble -> even k, high -> odd k). f32 magic 0x43000000|(nib<<16) =
// 128+nib exactly; (val-136)*s via one fma with c=-136*s; pack to bf16 pairs.
// ---------------------------------------------------------------------------
__device__ __forceinline__ s16x8 dequant8_bf16(int4 p, float s, float c) {
  union { u32 u[4]; s16x8 v; } r;
  const int d[4] = {p.x, p.y, p.z, p.w};
  #pragma unroll
  for (int e = 0; e < 4; ++e) {
    u32 ve = 0x43000000u | (((u32)d[e] << 16) & 0x000F0000u);
    u32 vo = 0x43000000u | (((u32)d[e] << 12) & 0x000F0000u);
    float fe = fmaf(magicf(ve), s, c);
    float fo = fmaf(magicf(vo), s, c);
    r.u[e] = cvt_pk_bf16(fe, fo);
  }
  return r.v;
}

// ---------------------------------------------------------------------------
// FAST PATH (mode==2, bf16 inputs).
// BM=128, BN=256, BK=64. 4 waves 1x4 along n; each wave 128x64 (acc 8x4).
// A: global_load_lds double-buffered, XOR-swizzled (linear LDS dest +
//    pre-swizzled global src + swizzled ds_read). B: in-register dequant.
// ---------------------------------------------------------------------------
__global__ __launch_bounds__(256, 2) void q4gemm_bf16_kernel(
    const u16* __restrict__ xb,      // bf16 bits
    const int* __restrict__ packed,  // 1 byte per int32, 2 nibbles
    const u16* __restrict__ scb,     // bf16 bits
    float* __restrict__ out,
    const int* __restrict__ modep)
{
  const int mode = modep ? modep[0] : 2;
  if (mode != 2) return;

  __shared__ u16 As[2][128 * 64];    // 32 KiB total

  const int tid  = threadIdx.x;
  const int lane = tid & 63;
  const int wv   = tid >> 6;

  // XCD-aware bijective swizzle: grid 2752 = 8 * 344; bm-minor so same-XCD
  // neighbors share the 2MB packed panel in L2.
  int bid = blockIdx.x;
  int f   = (bid & 7) * 344 + (bid >> 3);
  int bn  = f / 64;
  int bm  = f - bn * 64;
  const int n0 = bn * 256;
  const int m0 = bm * 128;

  // ---- A staging addresses (pre-swizzled source; LDS[row][c]=G[row][c^(row&7)])
  const int srow  = lane >> 3;             // 0..7
  const int sperm = (lane & 7) ^ srow;
  const u16* abase[4];
  #pragma unroll
  for (int q = 0; q < 4; ++q) {
    int row = (wv * 4 + q) * 8 + srow;
    abase[q] = xb + (long)(m0 + row) * K_DIM + sperm * 8;
  }

  // ---- B addresses: fragment (j,kkc) = int4 of packed row col, 8 weights
  const int ln15 = lane & 15;
  const int lk   = lane >> 4;              // k-chunk 0..3
  int pbase[4], sbase[4];
  #pragma unroll
  for (int j = 0; j < 4; ++j) {
    int col  = n0 + wv * 64 + j * 16 + ln15;
    pbase[j] = col * (K_DIM / 2) + lk * 4; // dword index (fits 32-bit)
    sbase[j] = col * GROUPS;
  }

  f32x4 acc[8][4];
  #pragma unroll
  for (int i = 0; i < 8; ++i)
    #pragma unroll
    for (int j = 0; j < 4; ++j)
      acc[i][j] = f32x4{0.f, 0.f, 0.f, 0.f};

  // ---- prologue: stage tile 0 into buf 0; prefetch scales g=0
  #pragma unroll
  for (int q = 0; q < 4; ++q)
    __builtin_amdgcn_global_load_lds(
        (const __attribute__((address_space(1))) void*)abase[q],
        (__attribute__((address_space(3))) void*)&As[0][(wv * 4 + q) * 512],
        16, 0, 0);

  u32 snext[4];
  #pragma unroll
  for (int j = 0; j < 4; ++j) snext[j] = scb[sbase[j]];

  __syncthreads();

  for (int g = 0; g < GROUPS; ++g) {
    float s[4], c[4];
    #pragma unroll
    for (int j = 0; j < 4; ++j) {
      s[j] = magicf(snext[j] << 16);
      c[j] = -136.0f * s[j];
    }
    if (g < GROUPS - 1) {
      #pragma unroll
      for (int j = 0; j < 4; ++j) snext[j] = scb[sbase[j] + g + 1];
    }

    #pragma unroll
    for (int half = 0; half < 2; ++half) {
      const int t   = g * 2 + half;
      const int cur = half;                // t & 1

      // B raw: 8 x int4 (all fragments of this K-tile), issued early
      int4 raw[4][2];
      #pragma unroll
      for (int j = 0; j < 4; ++j) {
        const int4* pp = (const int4*)(packed + pbase[j] + t * 32);
        raw[j][0] = pp[0];
        raw[j][1] = pp[4];                 // +16 dwords
      }

      // stage A(t+1) into the other buffer — in flight through the MFMAs
      if (t < 63) {
        #pragma unroll
        for (int q = 0; q < 4; ++q)
          __builtin_amdgcn_global_load_lds(
              (const __attribute__((address_space(1))) void*)(abase[q] + (t + 1) * 64),
              (__attribute__((address_space(3))) void*)&As[cur ^ 1][(wv * 4 + q) * 512],
              16, 0, 0);
      }

      #pragma unroll
      for (int kkc = 0; kkc < 2; ++kkc) {
        s16x8 af[8];
        #pragma unroll
        for (int i = 0; i < 8; ++i) {
          int row  = i * 16 + ln15;
          int slot = (kkc * 4 + lk) ^ (row & 7);   // XOR-swizzled read
          af[i] = *(const s16x8*)&As[cur][row * 64 + slot * 8];
        }
        #pragma unroll
        for (int j = 0; j < 4; ++j) {
          s16x8 bf = dequant8_bf16(raw[j][kkc], s[j], c[j]);
          #pragma unroll
          for (int i = 0; i < 8; ++i)
            acc[i][j] = __builtin_amdgcn_mfma_f32_16x16x32_bf16(af[i], bf, acc[i][j], 0, 0, 0);
        }
      }
      __syncthreads();
    }
  }

  // ---- epilogue: C/D layout col=lane&15, row=(lane>>4)*4+reg
  #pragma unroll
  for (int i = 0; i < 8; ++i) {
    int r0 = m0 + i * 16 + (lane >> 4) * 4;
    #pragma unroll
    for (int j = 0; j < 4; ++j) {
      int cc = n0 + wv * 64 + j * 16 + ln15;
      #pragma unroll
      for (int r = 0; r < 4; ++r)
        out[(long)(r0 + r) * N_DIM + cc] = acc[i][j][r];
    }
  }
}

// ---------------------------------------------------------------------------
// SLOW FALLBACK (modes 0/1) — R1's verified kernel; early-out on mode 2.
// ---------------------------------------------------------------------------
__global__ __launch_bounds__(256) void q4gemm_slow_kernel(
    const void* __restrict__ xraw,
    const int*  __restrict__ packed,
    const void* __restrict__ scraw,
    float* __restrict__ out,
    const int* __restrict__ modep)
{
  const int mode = modep ? modep[0] : 2;
  if (mode == 2) return;

  __shared__ u16 Asl[128 * LDSK];
  __shared__ u16 Bsl[128 * LDSK];

  const int tid  = threadIdx.x;
  const int lane = tid & 63;
  const int wv   = tid >> 6;
  const int wm   = (wv >> 1) * 64;
  const int wn   = (wv & 1) * 64;
  const int n0   = blockIdx.x * 128;
  const int m0   = blockIdx.y * 128;

  f32x4 acc[4][4];
  #pragma unroll
  for (int i = 0; i < 4; ++i)
    #pragma unroll
    for (int j = 0; j < 4; ++j)
      acc[i][j] = f32x4{0.f, 0.f, 0.f, 0.f};

  const int lrow16 = lane & 15;
  const int lk8    = (lane >> 4) * 8;

  for (int k0 = 0; k0 < K_DIM; k0 += 64) {
    if (mode == 0) {
      const float* xf = (const float*)xraw;
      #pragma unroll
      for (int it = 0; it < 4; ++it) {
        int s = tid + it * 256;
        int row = s >> 3, c8 = (s & 7) * 8;
        const float4* p = (const float4*)(xf + (long)(m0 + row) * K_DIM + k0 + c8);
        float4 v0 = p[0], v1 = p[1];
        u16 tmp[8] = { f2bf(v0.x), f2bf(v0.y), f2bf(v0.z), f2bf(v0.w),
                       f2bf(v1.x), f2bf(v1.y), f2bf(v1.z), f2bf(v1.w) };
        *(s16x8*)&Asl[row * LDSK + c8] = *(const s16x8*)tmp;
      }
    } else {
      const u16* xhh = (const u16*)xraw;   // fp16 bits -> bf16
      #pragma unroll
      for (int it = 0; it < 4; ++it) {
        int s = tid + it * 256;
        int row = s >> 3, c8 = (s & 7) * 8;
        s16x8 v = *(const s16x8*)(xhh + (long)(m0 + row) * K_DIM + k0 + c8);
        u16 tmp[8];
        #pragma unroll
        for (int j = 0; j < 8; ++j) tmp[j] = f2bf(h2f((u16)v[j]));
        *(s16x8*)&Asl[row * LDSK + c8] = *(const s16x8*)tmp;
      }
    }

    {
      int row  = tid >> 1;
      int half = tid & 1;
      int srw  = n0 + row;
      int g    = k0 >> 7;
      float scale;
      if (mode == 0) scale = ((const float*)scraw)[(long)srw * GROUPS + g];
      else           scale = h2f(((const u16*)scraw)[(long)srw * GROUPS + g]);

      const int4* pp = (const int4*)(packed + (long)srw * (K_DIM / 2) + (k0 >> 1) + half * 16);
      #pragma unroll
      for (int j = 0; j < 4; ++j) {
        int4 pv = pp[j];
        int vals[4] = {pv.x, pv.y, pv.z, pv.w};
        u16 w[8];
        #pragma unroll
        for (int e = 0; e < 4; ++e) {
          int b = vals[e] & 255;
          w[e * 2]     = f2bf(scale * (float)((b & 15) - 8));
          w[e * 2 + 1] = f2bf(scale * (float)(((b >> 4) & 15) - 8));
        }
        int i0 = half * 16 + j * 4;
        *(s16x8*)&Bsl[row * LDSK + i0 * 2] = *(const s16x8*)w;
      }
    }
    __syncthreads();

    #pragma unroll
    for (int kk = 0; kk < 64; kk += 32) {
      s16x8 af[4], bfr[4];
      int klane = kk + lk8;
      #pragma unroll
      for (int i = 0; i < 4; ++i)
        af[i] = *(const s16x8*)&Asl[(wm + i * 16 + lrow16) * LDSK + klane];
      #pragma unroll
      for (int i = 0; i < 4; ++i)
        bfr[i] = *(const s16x8*)&Bsl[(wn + i * 16 + lrow16) * LDSK + klane];
      #pragma unroll
      for (int i = 0; i < 4; ++i)
        #pragma unroll
        for (int j = 0; j < 4; ++j)
          acc[i][j] = __builtin_amdgcn_mfma_f32_16x16x32_bf16(af[i], bfr[j], acc[i][j], 0, 0, 0);
    }
    __syncthreads();
  }

  #pragma unroll
  for (int i = 0; i < 4; ++i) {
    int rbase = m0 + wm + i * 16 + ((lane >> 4) * 4);
    #pragma unroll
    for (int j = 0; j < 4; ++j) {
      int c = n0 + wn + j * 16 + (lane & 15);
      #pragma unroll
      for (int r = 0; r < 4; ++r)
        out[(long)(rbase + r) * N_DIM + c] = acc[i][j][r];
    }
  }
}

extern "C" void kernel_launch(void* const* d_in, const int* in_sizes, int n_in,
                              void* d_out, int out_size, void* d_ws, size_t ws_size,
                              hipStream_t stream) {
  const void* x      = d_in[0];
  const int*  packed = (const int*)d_in[1];
  const void* scales = d_in[2];
  float* out = (float*)d_out;

  int* mode_flag = nullptr;
  if (ws_size >= 4) {
    mode_flag = (int*)d_ws;
    probe_mode_kernel<<<dim3(1), dim3(256), 0, stream>>>(scales, mode_flag);
  }

  // fast path (bf16): 2752 blocks = (11008/256) * (8192/128)
  q4gemm_bf16_kernel<<<dim3(2752), dim3(256), 0, stream>>>(
      (const u16*)x, packed, (const u16*)scales, out, mode_flag);

  // fallback for modes 0/1 (early-outs if mode==2)
  q4gemm_slow_kernel<<<dim3(N_DIM / 128, M_DIM / 128), dim3(256), 0, stream>>>(
      x, packed, scales, out, mode_flag);
}